// Round 10
// baseline (277.956 us; speedup 1.0000x reference)
//
#include <hip/hip_runtime.h>
#include <math.h>

#define NB 1024
#define NF 36
#define ED 256
#define NK 8
#define NN2 1296   // 36*36
#define QPK 162    // 1296/8

typedef _Float16 f16;
typedef f16 f16x8 __attribute__((ext_vector_type(8)));
typedef float f32x4 __attribute__((ext_vector_type(4)));

#define WXSTR 136     // f16 per Wx half-row (128 + 8 pad)
#define NFRAG 1536    // 3 row-tiles * 8 kc * 64 lanes, f16x8 each

// ---- mega-kernel LDS layout (dynamic, ~73.2 KB -> 2 blocks/CU) ----
#define XH_OFF  0                       // 24576
#define XL_OFF  24576                   // 24576
#define R_OFF   49152                   // reusable region, 23424 B:
                                        //   staging: Xtmp 16*260*4=16640 | VfH 8192 + VfL 8192
                                        //   k-loop:  Wxh 13056 | Tbuf 5184 | lgBuf 5184
#define WXH_OFF R_OFF
#define TB_OFF  (R_OFF + 13056)
#define LG_OFF  (R_OFF + 18240)
#define V12_OFF (R_OFF + 23424)         // 16*36*4 = 2304
#define U_OFF   (V12_OFF + 2304)        // 40
#define SMEM_MAIN (U_OFF + 40)          // 74920

__device__ __forceinline__ f32x4 mfma16(f16x8 a, f16x8 b, f32x4 c) {
    return __builtin_amdgcn_mfma_f32_16x16x32_f16(a, b, c, 0, 0, 0);
}

// ---- pack W[k][c][d] -> B-fragment order, HI only, scaled by 16 ----
__global__ __launch_bounds__(256) void prep_w(const float* __restrict__ W,
                                              f16x8* __restrict__ WfH) {
    int idx = blockIdx.x * 256 + threadIdx.x;   // 65536 total
    int dox = idx & 31;
    int c   = (idx >> 5) & 255;
    int k   = idx >> 13;
    const float* src = W + ((size_t)(k * 256 + c)) * 256 + dox * 8;
    float4 a = *(const float4*)src;
    float4 b = *(const float4*)(src + 4);
    float v[8] = {a.x, a.y, a.z, a.w, b.x, b.y, b.z, b.w};
    f16x8 hi;
    #pragma unroll
    for (int j = 0; j < 8; ++j) hi[j] = (f16)(v[j] * 16.0f);
    int kc = dox >> 2, qd = dox & 3, ct = c >> 4;
    WfH[((k * 16 + ct) * 8 + kc) * 64 + qd * 16 + (c & 15)] = hi;
}

// Fused per-b kernel: in-LDS X split + v12 + 8-k loop + softmax + store.
__global__ __launch_bounds__(256, 2) void ntn_mega(
    const float* __restrict__ texts, const f16x8* __restrict__ WfH,
    const float* __restrict__ Wb,
    const float* __restrict__ V1w, const float* __restrict__ V1b,
    const float* __restrict__ V2w, const float* __restrict__ V2b,
    const float* __restrict__ Uw,  const float* __restrict__ Ubp,
    float* __restrict__ out)
{
    extern __shared__ char smem[];
    f16x8* Xh   = (f16x8*)(smem + XH_OFF);
    f16x8* Xl   = (f16x8*)(smem + XL_OFF);
    float* Xtmp = (float*)(smem + R_OFF);        // staging overlay
    f16x8* VfH  = (f16x8*)(smem + R_OFF);        // staging overlay
    f16x8* VfL  = (f16x8*)(smem + R_OFF + 8192);
    f16*   Wxh  = (f16*)(smem + WXH_OFF);
    float* Tbuf = (float*)(smem + TB_OFF);       // 1296 f32 (per-k T)
    float* lgBuf= (float*)(smem + LG_OFF);       // 1296 f32 (all-k logits)
    float* v12b = (float*)(smem + V12_OFF);      // [16][36]
    float* Uws  = (float*)(smem + U_OFF);

    const int b    = blockIdx.x;
    const int t    = threadIdx.x;
    const int wave = t >> 6;
    const int lane = t & 63;
    const int quad = lane >> 4;
    const int l15  = lane & 15;

    const float* xb = texts + (size_t)b * NF * ED;

    if (t < 8) Uws[t] = Uw[t];
    if (t == 8) Uws[8] = Ubp[0];

    // ===== stage X: 3 chunks of 16 rows, coalesced f32 -> LDS -> split frags =====
    for (int cc = 0; cc < 3; ++cc) {
        const int nrows = (cc == 2) ? 4 : 16;    // rows 32..35 in chunk 2
        for (int i = t; i < nrows * 64; i += 256) {
            int r = i >> 6, c4 = (i & 63) << 2;
            *(float4*)&Xtmp[r * 260 + c4] = *(const float4*)(xb + (cc * 16 + r) * ED + c4);
        }
        __syncthreads();
        #pragma unroll
        for (int i0 = 0; i0 < 2; ++i0) {
            int i2 = t + i0 * 256;               // [0,512): frag rt=cc
            int kc = i2 >> 6, lane2 = i2 & 63;
            int q = lane2 >> 4, lr = lane2 & 15;
            f16x8 hi, lo;
            if (cc * 16 + lr < NF) {
                const float* s = &Xtmp[lr * 260 + kc * 32 + q * 8];
                #pragma unroll
                for (int j = 0; j < 8; ++j) {
                    float v = s[j];
                    f16 h = (f16)v;
                    hi[j] = h;
                    lo[j] = (f16)(v - (float)h);
                }
            } else {
                #pragma unroll
                for (int j = 0; j < 8; ++j) { hi[j] = (f16)0.f; lo[j] = (f16)0.f; }
            }
            Xh[cc * 512 + i2] = hi;
            Xl[cc * 512 + i2] = lo;
        }
        __syncthreads();
    }

    // ===== V fragments + v12 via split MFMA =====
    #pragma unroll
    for (int i0 = 0; i0 < 2; ++i0) {
        int i = t + i0 * 256;                    // [0,512)
        int kc = (i >> 6) & 7, lane2 = i & 63;
        int q = lane2 >> 4, col = lane2 & 15;
        int which = col >> 3, kk = col & 7;
        const float* src = (which ? V2w : V1w) + kk * 256 + kc * 32 + q * 8;
        f16x8 hi, lo;
        #pragma unroll
        for (int j = 0; j < 8; ++j) {
            float sv = src[j] * 16.0f;
            f16 h = (f16)sv;
            hi[j] = h;
            lo[j] = (f16)(sv - (float)h);
        }
        VfH[i] = hi;
        VfL[i] = lo;
    }
    __syncthreads();
    if (wave < 3) {
        f32x4 acc = (f32x4){0.f, 0.f, 0.f, 0.f};
        #pragma unroll
        for (int kc = 0; kc < 8; ++kc) {
            f16x8 ah = Xh[(wave * 8 + kc) * 64 + lane];
            f16x8 al = Xl[(wave * 8 + kc) * 64 + lane];
            f16x8 bh = VfH[kc * 64 + lane];
            f16x8 bl = VfL[kc * 64 + lane];
            acc = mfma16(ah, bh, acc);
            acc = mfma16(ah, bl, acc);
            acc = mfma16(al, bh, acc);
        }
        const int which = l15 >> 3, kk = l15 & 7;
        const float bias = which ? V2b[kk] : V1b[kk];
        #pragma unroll
        for (int r = 0; r < 4; ++r) {
            const int n = wave * 16 + quad * 4 + r;
            if (n < NF) v12b[l15 * NF + n] = acc[r] * 0.0625f + bias;
        }
    }
    __syncthreads();   // staging region free; v12b/Uws visible

    // ===== k-loop: phase1 -> Wxh -> phase2 -> T -> U-dot -> lgBuf =====
    for (int k = 0; k < NK; ++k) {
        const f16x8* WfHk = WfH + (size_t)k * 16 * 8 * 64;
        float wbv[2][2];
        #pragma unroll
        for (int h = 0; h < 2; ++h) {
            wbv[h][0] = Wb[k * ED + (h * 8 + wave) * 16 + l15];
            wbv[h][1] = Wb[k * ED + (h * 8 + wave + 4) * 16 + l15];
        }

        f32x4 sacc[3];
        #pragma unroll
        for (int i = 0; i < 3; ++i) sacc[i] = (f32x4){0.f, 0.f, 0.f, 0.f};

        for (int h = 0; h < 2; ++h) {
            // phase 1: Wx[:, half h] = X * W[k]^T (AhBh + AlBh, W-hi only)
            f32x4 acc[3][2];
            #pragma unroll
            for (int i = 0; i < 3; ++i) { acc[i][0] = (f32x4){0,0,0,0}; acc[i][1] = (f32x4){0,0,0,0}; }
            const int ct0 = h * 8 + wave;
            const int ct1 = ct0 + 4;
            #pragma unroll 2
            for (int kc = 0; kc < 8; ++kc) {
                f16x8 ah[3], al[3];
                #pragma unroll
                for (int rt = 0; rt < 3; ++rt) {
                    ah[rt] = Xh[(rt * 8 + kc) * 64 + lane];
                    al[rt] = Xl[(rt * 8 + kc) * 64 + lane];
                }
                f16x8 bh0 = WfHk[(ct0 * 8 + kc) * 64 + lane];
                f16x8 bh1 = WfHk[(ct1 * 8 + kc) * 64 + lane];
                #pragma unroll
                for (int rt = 0; rt < 3; ++rt) {
                    acc[rt][0] = mfma16(ah[rt], bh0, acc[rt][0]);
                    acc[rt][0] = mfma16(al[rt], bh0, acc[rt][0]);
                    acc[rt][1] = mfma16(ah[rt], bh1, acc[rt][1]);
                    acc[rt][1] = mfma16(al[rt], bh1, acc[rt][1]);
                }
            }
            __syncthreads();   // prior phase-2 Wxh readers + prior-k U-dot Tbuf readers done
            #pragma unroll
            for (int rt = 0; rt < 3; ++rt) {
                #pragma unroll
                for (int j2 = 0; j2 < 2; ++j2) {
                    const float wb = wbv[h][j2];
                    const int cl = (j2 ? (wave + 4) : wave) * 16 + l15;
                    #pragma unroll
                    for (int r = 0; r < 4; ++r) {
                        const int row = rt * 16 + quad * 4 + r;
                        Wxh[row * WXSTR + cl] = (f16)(acc[rt][j2][r] * 0.0625f + wb);
                    }
                }
            }
            __syncthreads();
            // phase 2: S += Wxh * (Xh + Xl)^T (9 tiles over 4 waves)
            #pragma unroll
            for (int it = 0; it < 3; ++it) {
                const int p = wave + it * 4;
                if (p < 9) {
                    const int nt = p / 3, mt = p % 3;
                    const f16* wxh_p = Wxh + (nt * 16 + l15) * WXSTR + quad * 8;
                    #pragma unroll
                    for (int kc2 = 0; kc2 < 4; ++kc2) {
                        f16x8 pah = *(const f16x8*)(wxh_p + kc2 * 32);
                        f16x8 pbh = Xh[(mt * 8 + h * 4 + kc2) * 64 + lane];
                        f16x8 pbl = Xl[(mt * 8 + h * 4 + kc2) * 64 + lane];
                        sacc[it] = mfma16(pah, pbh, sacc[it]);
                        sacc[it] = mfma16(pah, pbl, sacc[it]);
                    }
                }
            }
        }

        // epilogue: T = tanh(S + v1 + v2) -> Tbuf
        #pragma unroll
        for (int it = 0; it < 3; ++it) {
            const int p = wave + it * 4;
            if (p < 9) {
                const int nt = p / 3, mt = p % 3;
                const int m = mt * 16 + l15;
                if (m < NF) {
                    #pragma unroll
                    for (int r = 0; r < 4; ++r) {
                        const int n = nt * 16 + quad * 4 + r;
                        if (n < NF) {
                            float sv = sacc[it][r] + v12b[k * NF + n] + v12b[(8 + k) * NF + m];
                            float e = __expf(2.f * sv);
                            Tbuf[n * NF + m] = 1.f - 2.f / (e + 1.f);
                        }
                    }
                }
            }
        }
        __syncthreads();
        if (t < QPK) {
            const float* tp = Tbuf + t * 8;
            float lg = Uws[8];
            #pragma unroll
            for (int j = 0; j < 8; ++j) lg += Uws[j] * tp[j];
            lgBuf[k * QPK + t] = lg;
        }
    }
    __syncthreads();

    // ===== fused softmax over lgBuf rows (n-major: row n = [n*36, n*36+36)) =====
    if (t < NF) {
        float* row = lgBuf + t * NF;
        float mx = -INFINITY;
        #pragma unroll 4
        for (int j = 0; j < NF; ++j) mx = fmaxf(mx, row[j]);
        float sm = 0.f;
        #pragma unroll 4
        for (int j = 0; j < NF; ++j) { float e = __expf(row[j] - mx); sm += e; row[j] = e; }
        const float inv = 1.f / sm;
        #pragma unroll 4
        for (int j = 0; j < NF; ++j) row[j] *= inv;
    }
    __syncthreads();
    for (int i = t; i < NN2; i += 256)
        out[(size_t)b * NN2 + i] = lgBuf[i];
}

extern "C" void kernel_launch(void* const* d_in, const int* in_sizes, int n_in,
                              void* d_out, int out_size, void* d_ws, size_t ws_size,
                              hipStream_t stream) {
    const float* texts = (const float*)d_in[0];
    const float* W     = (const float*)d_in[1];
    const float* Wb    = (const float*)d_in[2];
    const float* V1w   = (const float*)d_in[3];
    const float* V1b   = (const float*)d_in[4];
    const float* V2w   = (const float*)d_in[5];
    const float* V2b   = (const float*)d_in[6];
    const float* Uw    = (const float*)d_in[7];
    const float* Ub    = (const float*)d_in[8];

    f16x8* WfH = (f16x8*)d_ws;    // 1 MiB
    float* out = (float*)d_out;

    hipFuncSetAttribute((const void*)ntn_mega,
                        hipFuncAttributeMaxDynamicSharedMemorySize, SMEM_MAIN);

    prep_w<<<256, 256, 0, stream>>>(W, WfH);
    ntn_mega<<<NB, 256, SMEM_MAIN, stream>>>(texts, WfH, Wb, V1w, V1b, V2w, V2b, Uw, Ub, out);
}